// Round 15
// baseline (581.931 us; speedup 1.0000x reference)
//
#include <hip/hip_runtime.h>
#include <math.h>

#define N_NODES 10000
#define N_EDGES 160000
#define BATCH 32
#define HLEN 12
#define KORD 25
#define G1 32
#define NCLS 10
#define BH 384   /* BATCH*HLEN */
#define BG 1024  /* BATCH*G1  */
#define NQ 8     /* fallback path: BH split into 8 slices of 48 */
#define QW 48
#define QU 24
#define RU 192   /* big path: uints per full bf16 row (384 values) */
#define FC1_BLOCKS 313
#define EIN_BLOCKS 1250   /* 8 nodes per block (2 per wave) */
#define RED1_BLOCKS 10
#define WPK_N (KORD * 192)  /* w_pk uints: [KORD][3][2][32] */

typedef unsigned int uint32;
typedef unsigned short ushort16;
typedef __attribute__((ext_vector_type(8))) short short8v;
typedef __attribute__((ext_vector_type(4))) float f32x4;
typedef __attribute__((ext_vector_type(2))) unsigned int uint2v;

struct U3 { uint32 x, y, z; };  // 12B, 4-aligned -> global_load_dwordx3

__device__ __forceinline__ float bf16lo(uint32 u) { return __uint_as_float(u << 16); }
__device__ __forceinline__ float bf16hi(uint32 u) { return __uint_as_float(u & 0xffff0000u); }
__device__ __forceinline__ uint32 pack_bf16(float a, float b) {
    uint32 ua = __float_as_uint(a), ub = __float_as_uint(b);
    ua = (ua + 0x7fffu + ((ua >> 16) & 1u)) >> 16;
    ub = (ub + 0x7fffu + ((ub >> 16) & 1u)) & 0xffff0000u;
    return ua | ub;
}
__device__ __forceinline__ ushort16 f2bf(float a) {
    uint32 ua = __float_as_uint(a);
    return (ushort16)((ua + 0x7fffu + ((ua >> 16) & 1u)) >> 16);
}

// ---------------- CSR build ----------------
__global__ void deg_kernel(const int* __restrict__ row, int* __restrict__ cnt) {
    int e = blockIdx.x * 256 + threadIdx.x;
    if (e < N_EDGES) atomicAdd(&cnt[row[e]], 1);
}

__global__ void dinv_kernel(const int* __restrict__ cnt, float* __restrict__ dinv) {
    int n = blockIdx.x * 256 + threadIdx.x;
    if (n < N_NODES) {
        int d = cnt[n];
        dinv[n] = (d > 0) ? 1.0f / sqrtf((float)d) : 0.0f;
    }
}

__global__ __launch_bounds__(1024) void scan_kernel(const int* __restrict__ cnt,
                                                    int* __restrict__ rowstart) {
    __shared__ int sums[1024];
    int t = threadIdx.x;
    const int per = 10;
    int base = t * per;
    int s = 0;
    for (int i = 0; i < per; i++) { int idx = base + i; if (idx < N_NODES) s += cnt[idx]; }
    sums[t] = s;
    __syncthreads();
    for (int off = 1; off < 1024; off <<= 1) {
        int v = 0;
        if (t >= off) v = sums[t - off];
        __syncthreads();
        sums[t] += v;
        __syncthreads();
    }
    int run = sums[t] - s;
    for (int i = 0; i < per; i++) {
        int idx = base + i;
        if (idx < N_NODES) { rowstart[idx] = run; run += cnt[idx]; }
    }
    if (t == 1023) rowstart[N_NODES] = run;
}

__global__ void scatter_kernel(const int* __restrict__ row, const int* __restrict__ col,
                               const float* __restrict__ dinv,
                               const int* __restrict__ rowstart, int* __restrict__ cursor,
                               int2* __restrict__ csr_pack) {
    int e = blockIdx.x * 256 + threadIdx.x;
    if (e < N_EDGES) {
        int r = row[e], c = col[e];
        int p = rowstart[r] + atomicAdd(&cursor[r], 1);
        float nrm = -dinv[r] * dinv[c];
        csr_pack[p] = make_int2(c, __float_as_int(nrm));
    }
}

// ---------------- bf16 weight pre-pack: w_pk[k][g][j2][f] ----------------
__global__ void wpack_kernel(const float* __restrict__ conv_w, uint32* __restrict__ w_pk) {
    int idx = blockIdx.x * 256 + threadIdx.x;
    if (idx >= WPK_N) return;
    int k = idx / 192;
    int r = idx % 192;
    int g = r >> 6;
    int j2 = (r >> 5) & 1;
    int f = r & 31;
    int h0 = 4 * g + 2 * j2;
    float a = conv_w[(size_t)k * BH + h0 * G1 + f];
    float b = conv_w[(size_t)k * BH + (h0 + 1) * G1 + f];
    w_pk[idx] = pack_bf16(a, b);
}

// ================= BIG PATH (full-row layout [k][node][192 uints]) =================
__global__ __launch_bounds__(256) void fft_full_kernel(const float* __restrict__ x,
                                                       uint32* __restrict__ T0) {
    __shared__ float C[HLEN][HLEN];
    int t = threadIdx.x;
    if (t < HLEN * HLEN) {
        int k = t / HLEN, tt = t % HLEN;
        C[k][tt] = cosf(0.52359877559829887308f * (float)(k * tt)); // pi/6 * k*t
    }
    __syncthreads();
    int tid = blockIdx.x * 256 + t; // tid = n*32 + b
    if (tid >= N_NODES * BATCH) return;
    int n = tid >> 5, b = tid & 31;
    const float* xp = x + (size_t)b * (N_NODES * HLEN) + (size_t)n * HLEN;
    float xr[HLEN];
#pragma unroll
    for (int i = 0; i < HLEN; i++) xr[i] = xp[i];
    float s[HLEN];
#pragma unroll
    for (int k = 0; k < HLEN; k++) {
        float acc = 0.f;
#pragma unroll
        for (int i = 0; i < HLEN; i++) acc += xr[i] * C[k][i];
        s[k] = acc;
    }
    uint32* o = T0 + (size_t)n * RU + b * 6;
#pragma unroll
    for (int j = 0; j < 6; j++) o[j] = pack_bf16(s[2 * j], s[2 * j + 1]);
}

// ---------------- full-row SpMM (dwordx3 lanes; 8-edge chunks, 24 loads in flight) ----------------
__global__ __launch_bounds__(256) void spmm_full_kernel(
    const uint32* __restrict__ zcur, const uint32* __restrict__ zprev,
    uint32* __restrict__ znext,
    const int* __restrict__ rowstart, const int2* __restrict__ csr_pack,
    float alpha, float beta) {
    int t = threadIdx.x;
    int wv = t >> 6, l = t & 63;
    int node = blockIdx.x * 4 + wv;
    int lo3 = 3 * l;

    float a0 = 0.f, a1 = 0.f, a2 = 0.f, a3 = 0.f, a4 = 0.f, a5 = 0.f;
    int e0 = rowstart[node], e1 = rowstart[node + 1];
    int e = e0;
    if ((e & 1) && e < e1) { // odd head
        int2 p = csr_pack[e];
        float nrm = __int_as_float(p.y);
        U3 u = *(const U3*)(zcur + p.x * RU + lo3);
        a0 += nrm * bf16lo(u.x); a1 += nrm * bf16hi(u.x);
        a2 += nrm * bf16lo(u.y); a3 += nrm * bf16hi(u.y);
        a4 += nrm * bf16lo(u.z); a5 += nrm * bf16hi(u.z);
        e++;
    }
    const int4* csr4 = (const int4*)csr_pack;
    int npair = (e1 - e) >> 1;
    int base = e >> 1;
    int nch = npair >> 2; // chunks of 8 edges (4 int4 pairs)
    if (nch > 0) {
        int4 c0 = csr4[base], c1 = csr4[base + 1];
        int4 c2 = csr4[base + 2], c3 = csr4[base + 3];
        for (int ch = 0; ch < nch; ch++) {
            int4 p0 = c0, p1 = c1, p2 = c2, p3 = c3;
            if (ch + 1 < nch) {
                int b2 = base + 4 * (ch + 1);
                c0 = csr4[b2];     c1 = csr4[b2 + 1];
                c2 = csr4[b2 + 2]; c3 = csr4[b2 + 3];
            }
            // 8 gathers issued back-to-back (24 dwords in flight)
            U3 uA = *(const U3*)(zcur + p0.x * RU + lo3);
            U3 uB = *(const U3*)(zcur + p0.z * RU + lo3);
            U3 uC = *(const U3*)(zcur + p1.x * RU + lo3);
            U3 uD = *(const U3*)(zcur + p1.z * RU + lo3);
            U3 uE = *(const U3*)(zcur + p2.x * RU + lo3);
            U3 uF = *(const U3*)(zcur + p2.z * RU + lo3);
            U3 uG = *(const U3*)(zcur + p3.x * RU + lo3);
            U3 uH = *(const U3*)(zcur + p3.z * RU + lo3);
            float nA = __int_as_float(p0.y), nB = __int_as_float(p0.w);
            float nC = __int_as_float(p1.y), nD = __int_as_float(p1.w);
            float nE = __int_as_float(p2.y), nF = __int_as_float(p2.w);
            float nG = __int_as_float(p3.y), nH = __int_as_float(p3.w);
            a0 += nA * bf16lo(uA.x) + nB * bf16lo(uB.x) + nC * bf16lo(uC.x) + nD * bf16lo(uD.x);
            a1 += nA * bf16hi(uA.x) + nB * bf16hi(uB.x) + nC * bf16hi(uC.x) + nD * bf16hi(uD.x);
            a2 += nA * bf16lo(uA.y) + nB * bf16lo(uB.y) + nC * bf16lo(uC.y) + nD * bf16lo(uD.y);
            a3 += nA * bf16hi(uA.y) + nB * bf16hi(uB.y) + nC * bf16hi(uC.y) + nD * bf16hi(uD.y);
            a4 += nA * bf16lo(uA.z) + nB * bf16lo(uB.z) + nC * bf16lo(uC.z) + nD * bf16lo(uD.z);
            a5 += nA * bf16hi(uA.z) + nB * bf16hi(uB.z) + nC * bf16hi(uC.z) + nD * bf16hi(uD.z);
            a0 += nE * bf16lo(uE.x) + nF * bf16lo(uF.x) + nG * bf16lo(uG.x) + nH * bf16lo(uH.x);
            a1 += nE * bf16hi(uE.x) + nF * bf16hi(uF.x) + nG * bf16hi(uG.x) + nH * bf16hi(uH.x);
            a2 += nE * bf16lo(uE.y) + nF * bf16lo(uF.y) + nG * bf16lo(uG.y) + nH * bf16lo(uH.y);
            a3 += nE * bf16hi(uE.y) + nF * bf16hi(uF.y) + nG * bf16hi(uG.y) + nH * bf16hi(uH.y);
            a4 += nE * bf16lo(uE.z) + nF * bf16lo(uF.z) + nG * bf16lo(uG.z) + nH * bf16lo(uH.z);
            a5 += nE * bf16hi(uE.z) + nF * bf16hi(uF.z) + nG * bf16hi(uG.z) + nH * bf16hi(uH.z);
        }
        e += nch * 8;
    }
    for (; e + 2 <= e1; e += 2) { // tail pairs
        int4 p = csr4[e >> 1];
        U3 uA = *(const U3*)(zcur + p.x * RU + lo3);
        U3 uB = *(const U3*)(zcur + p.z * RU + lo3);
        float nA = __int_as_float(p.y), nB = __int_as_float(p.w);
        a0 += nA * bf16lo(uA.x) + nB * bf16lo(uB.x);
        a1 += nA * bf16hi(uA.x) + nB * bf16hi(uB.x);
        a2 += nA * bf16lo(uA.y) + nB * bf16lo(uB.y);
        a3 += nA * bf16hi(uA.y) + nB * bf16hi(uB.y);
        a4 += nA * bf16lo(uA.z) + nB * bf16lo(uB.z);
        a5 += nA * bf16hi(uA.z) + nB * bf16hi(uB.z);
    }
    if (e < e1) { // single tail
        int2 p = csr_pack[e];
        float nrm = __int_as_float(p.y);
        U3 u = *(const U3*)(zcur + p.x * RU + lo3);
        a0 += nrm * bf16lo(u.x); a1 += nrm * bf16hi(u.x);
        a2 += nrm * bf16lo(u.y); a3 += nrm * bf16hi(u.y);
        a4 += nrm * bf16lo(u.z); a5 += nrm * bf16hi(u.z);
    }
    int idx = node * RU + lo3;
    U3 pu = *(const U3*)(zprev + idx);
    U3 ov;
    ov.x = pack_bf16(alpha * a0 - beta * bf16lo(pu.x), alpha * a1 - beta * bf16hi(pu.x));
    ov.y = pack_bf16(alpha * a2 - beta * bf16lo(pu.y), alpha * a3 - beta * bf16hi(pu.y));
    ov.z = pack_bf16(alpha * a4 - beta * bf16lo(pu.z), alpha * a5 - beta * bf16hi(pu.z));
    *(U3*)(znext + idx) = ov;
}

// ---------------- MFMA einsum + relu + FC partial: 2 NODES PER WAVE ----------------
// Wave handles nodeA = bid*8 + wv*2 and nodeB = nodeA+1. B-fragments (weights) are
// node-invariant: loaded once per k, used by both nodes' MFMAs. 4 A-loads in flight.
__global__ __launch_bounds__(256) void einfc_mfma_kernel(
    const uint32* __restrict__ T_all,   // [KORD][N][RU]
    const uint32* __restrict__ w_pk,    // [KORD][3][2][32]
    const float* __restrict__ conv_b,
    const float* __restrict__ fc_w,     // [NCLS][N*G1]
    float* __restrict__ partials) {
    __shared__ float lgacc[BATCH * NCLS];
    int t = threadIdx.x;
    for (int i = t; i < BATCH * NCLS; i += 256) lgacc[i] = 0.f;
    __syncthreads();
    int wv = t >> 6, l = t & 63;
    int nodeA = blockIdx.x * 8 + wv * 2;
    int g = l >> 4;     // k-group
    int m = l & 15;     // row/col within 16-tile
    bool gz = (g == 3); // pad group (h 12..15)

    f32x4 aA00 = {0.f,0.f,0.f,0.f}, aA01 = {0.f,0.f,0.f,0.f};
    f32x4 aA10 = {0.f,0.f,0.f,0.f}, aA11 = {0.f,0.f,0.f,0.f};
    f32x4 aB00 = {0.f,0.f,0.f,0.f}, aB01 = {0.f,0.f,0.f,0.f};
    f32x4 aB10 = {0.f,0.f,0.f,0.f}, aB11 = {0.f,0.f,0.f,0.f};

    size_t aoff0 = (size_t)m * 6 + 2 * g;
    size_t aoff1 = (size_t)(m + 16) * 6 + 2 * g;

#pragma unroll
    for (int k = 0; k < KORD; k++) {
        const uint32* rowA = T_all + ((size_t)k * N_NODES + nodeA) * RU;
        const uint32* rowB = rowA + RU;
        uint2v vA0 = {0,0}, vA1 = {0,0}, vB0 = {0,0}, vB1 = {0,0};
        uint32 b0u0 = 0, b0u1 = 0, b1u0 = 0, b1u1 = 0;
        if (!gz) {
            vA0 = __builtin_nontemporal_load((const uint2v*)(rowA + aoff0));
            vA1 = __builtin_nontemporal_load((const uint2v*)(rowA + aoff1));
            vB0 = __builtin_nontemporal_load((const uint2v*)(rowB + aoff0));
            vB1 = __builtin_nontemporal_load((const uint2v*)(rowB + aoff1));
            const uint32* wp = w_pk + (k * 3 + g) * 64 + m;
            b0u0 = wp[0];  b0u1 = wp[32];
            b1u0 = wp[16]; b1u1 = wp[48];
        }
        union { short8v v; uint32 u[4]; } A0, A1, A2, A3, B0, B1;
        A0.u[0] = vA0.x; A0.u[1] = vA0.y; A0.u[2] = 0; A0.u[3] = 0;
        A1.u[0] = vA1.x; A1.u[1] = vA1.y; A1.u[2] = 0; A1.u[3] = 0;
        A2.u[0] = vB0.x; A2.u[1] = vB0.y; A2.u[2] = 0; A2.u[3] = 0;
        A3.u[0] = vB1.x; A3.u[1] = vB1.y; A3.u[2] = 0; A3.u[3] = 0;
        B0.u[0] = b0u0; B0.u[1] = b0u1; B0.u[2] = 0; B0.u[3] = 0;
        B1.u[0] = b1u0; B1.u[1] = b1u1; B1.u[2] = 0; B1.u[3] = 0;
        aA00 = __builtin_amdgcn_mfma_f32_16x16x32_bf16(A0.v, B0.v, aA00, 0, 0, 0);
        aA01 = __builtin_amdgcn_mfma_f32_16x16x32_bf16(A0.v, B1.v, aA01, 0, 0, 0);
        aA10 = __builtin_amdgcn_mfma_f32_16x16x32_bf16(A1.v, B0.v, aA10, 0, 0, 0);
        aA11 = __builtin_amdgcn_mfma_f32_16x16x32_bf16(A1.v, B1.v, aA11, 0, 0, 0);
        aB00 = __builtin_amdgcn_mfma_f32_16x16x32_bf16(A2.v, B0.v, aB00, 0, 0, 0);
        aB01 = __builtin_amdgcn_mfma_f32_16x16x32_bf16(A2.v, B1.v, aB01, 0, 0, 0);
        aB10 = __builtin_amdgcn_mfma_f32_16x16x32_bf16(A3.v, B0.v, aB10, 0, 0, 0);
        aB11 = __builtin_amdgcn_mfma_f32_16x16x32_bf16(A3.v, B1.v, aB11, 0, 0, 0);
    }

    // epilogue: relu + FC partial from C layout (col=lane&15, row=4*(lane>>4)+reg)
    float cb0 = conv_b[m];
    float cb1 = conv_b[m + 16];
#pragma unroll
    for (int nn = 0; nn < 2; nn++) {
        int node = nodeA + nn;
        float fw0[NCLS], fw1[NCLS];
#pragma unroll
        for (int c = 0; c < NCLS; c++) {
            const float* fp = fc_w + (size_t)c * (N_NODES * G1) + (size_t)node * G1;
            fw0[c] = fp[m];
            fw1[c] = fp[m + 16];
        }
#pragma unroll
        for (int bi = 0; bi < 2; bi++) {
            f32x4 aF, aS;
            if (nn == 0) { aF = bi ? aA10 : aA00; aS = bi ? aA11 : aA01; }
            else         { aF = bi ? aB10 : aB00; aS = bi ? aB11 : aB01; }
#pragma unroll
            for (int reg = 0; reg < 4; reg++) {
                float h0 = fmaxf(aF[reg] + cb0, 0.f);
                float h1 = fmaxf(aS[reg] + cb1, 0.f);
                int b = bi * 16 + 4 * g + reg;
#pragma unroll
                for (int c = 0; c < NCLS; c++) {
                    float sc = h0 * fw0[c] + h1 * fw1[c];
                    sc += __shfl_xor(sc, 1);
                    sc += __shfl_xor(sc, 2);
                    sc += __shfl_xor(sc, 4);
                    sc += __shfl_xor(sc, 8);
                    if (m == 0) atomicAdd(&lgacc[b * NCLS + c], sc);
                }
            }
        }
    }
    __syncthreads();
    for (int i = t; i < BATCH * NCLS; i += 256)
        partials[(size_t)blockIdx.x * (BATCH * NCLS) + i] = lgacc[i];
}

// ---------------- partial-reduce stage: EIN_BLOCKS rows -> 10 rows ----------------
__global__ __launch_bounds__(320) void red1_kernel(const float* __restrict__ partials,
                                                   float* __restrict__ red) {
    int t = threadIdx.x;
    int j = blockIdx.x;
    int i0 = j * (EIN_BLOCKS / RED1_BLOCKS);
    int i1 = i0 + (EIN_BLOCKS / RED1_BLOCKS);
    float s0 = 0.f, s1 = 0.f, s2 = 0.f, s3 = 0.f;
    int i = i0;
    for (; i + 4 <= i1; i += 4) {
        s0 += partials[(size_t)(i + 0) * (BATCH * NCLS) + t];
        s1 += partials[(size_t)(i + 1) * (BATCH * NCLS) + t];
        s2 += partials[(size_t)(i + 2) * (BATCH * NCLS) + t];
        s3 += partials[(size_t)(i + 3) * (BATCH * NCLS) + t];
    }
    for (; i < i1; i++) s0 += partials[(size_t)i * (BATCH * NCLS) + t];
    red[(size_t)j * (BATCH * NCLS) + t] = s0 + s1 + s2 + s3;
}

// ================= FALLBACK PATH (R8, proven; slice layout) =================
__global__ __launch_bounds__(256) void fft_slice_kernel(const float* __restrict__ x,
                                                        ushort16* __restrict__ xf) {
    __shared__ float C[HLEN][HLEN];
    int t = threadIdx.x;
    if (t < HLEN * HLEN) {
        int k = t / HLEN, tt = t % HLEN;
        C[k][tt] = cosf(0.52359877559829887308f * (float)(k * tt));
    }
    __syncthreads();
    int tid = blockIdx.x * 256 + t;
    if (tid >= N_NODES * BATCH) return;
    int n = tid >> 5, b = tid & 31;
    const float* xp = x + (size_t)b * (N_NODES * HLEN) + (size_t)n * HLEN;
    float xr[HLEN];
#pragma unroll
    for (int i = 0; i < HLEN; i++) xr[i] = xp[i];
    int q = b >> 2, bl = b & 3;
    ushort16* o = xf + ((size_t)q * N_NODES + n) * QW + bl * HLEN;
#pragma unroll
    for (int k = 0; k < HLEN; k++) {
        float s = 0.f;
#pragma unroll
        for (int i = 0; i < HLEN; i++) s += xr[i] * C[k][i];
        o[k] = f2bf(s);
    }
}

__global__ __launch_bounds__(256) void k0_split_kernel(const uint32* __restrict__ z,
                                                       float* __restrict__ out,
                                                       const float* __restrict__ w0) {
    __shared__ float zs[4][QW];
    __shared__ float wk[HLEN * G1];
    int t = threadIdx.x;
    int wv = t >> 6, lane = t & 63;
    int bid = blockIdx.x;
    int q = bid & 7;
    int node = (bid >> 3) * 4 + wv;
    for (int i = t; i < HLEN * G1; i += 256) wk[i] = w0[i];
    if (lane < QU) {
        uint32 u = z[((size_t)q * N_NODES + node) * QU + lane];
        zs[wv][2 * lane]     = bf16lo(u);
        zs[wv][2 * lane + 1] = bf16hi(u);
    }
    __syncthreads();
    float* op = out + (size_t)node * BG + q * 128;
#pragma unroll
    for (int r = 0; r < 2; r++) {
        int j = lane + 64 * r;
        int bl = j >> 5, f = j & 31;
        const float* zb = &zs[wv][bl * HLEN];
        float s = 0.f;
#pragma unroll
        for (int h = 0; h < HLEN; h++) s += zb[h] * wk[h * G1 + f];
        op[j] = s;
    }
}

__global__ __launch_bounds__(256) void spmm_fused_kernel(
    const uint32* __restrict__ zcur, const uint32* __restrict__ zprev,
    uint32* __restrict__ znext, float* __restrict__ out,
    const int* __restrict__ rowstart, const int2* __restrict__ csr_pack,
    const float* __restrict__ wkg, float alpha, float beta) {
    __shared__ float zs[4][QW];
    __shared__ float wk[HLEN * G1];
    int t = threadIdx.x;
    int wv = t >> 6, lane = t & 63;
    int bid = blockIdx.x;
    int q = bid & 7;
    int node = (bid >> 3) * 4 + wv;
    for (int i = t; i < HLEN * G1; i += 256) wk[i] = wkg[i];

    const uint32* zq = zcur + (size_t)q * ((size_t)N_NODES * QU);
    int g  = (lane >= 24) ? 1 : 0;
    int li = lane - g * 24;
    float a0 = 0.f, a1 = 0.f;
    int e0 = rowstart[node], e1 = rowstart[node + 1];
    if (lane < 48) {
        int e = e0;
        if ((e & 1) && e < e1) {
            if (g == 0) {
                int2 p = csr_pack[e];
                float nrm = __int_as_float(p.y);
                uint32 u = zq[p.x * QU + li];
                a0 += nrm * bf16lo(u);
                a1 += nrm * bf16hi(u);
            }
            e++;
        }
        const int4* csr4 = (const int4*)csr_pack;
        int npair = (e1 - e) >> 1;
        int base = e >> 1;
        int nchunk = npair >> 2;
        if (nchunk > 0) {
            int4 c0 = csr4[base];
            int4 c1 = csr4[base + 1];
            int4 c2 = csr4[base + 2];
            int4 c3 = csr4[base + 3];
            for (int ch = 0; ch < nchunk; ch++) {
                int4 p0 = c0, p1 = c1, p2 = c2, p3 = c3;
                if (ch + 1 < nchunk) {
                    int b2 = base + (ch + 1) * 4;
                    c0 = csr4[b2];
                    c1 = csr4[b2 + 1];
                    c2 = csr4[b2 + 2];
                    c3 = csr4[b2 + 3];
                }
                int col0 = g ? p0.z : p0.x;  float n0 = __int_as_float(g ? p0.w : p0.y);
                int col1 = g ? p1.z : p1.x;  float n1 = __int_as_float(g ? p1.w : p1.y);
                int col2 = g ? p2.z : p2.x;  float n2 = __int_as_float(g ? p2.w : p2.y);
                int col3 = g ? p3.z : p3.x;  float n3 = __int_as_float(g ? p3.w : p3.y);
                uint32 u0 = zq[col0 * QU + li];
                uint32 u1 = zq[col1 * QU + li];
                uint32 u2 = zq[col2 * QU + li];
                uint32 u3 = zq[col3 * QU + li];
                a0 += n0 * bf16lo(u0) + n1 * bf16lo(u1);
                a1 += n0 * bf16hi(u0) + n1 * bf16hi(u1);
                a0 += n2 * bf16lo(u2) + n3 * bf16lo(u3);
                a1 += n2 * bf16hi(u2) + n3 * bf16hi(u3);
            }
            e += nchunk * 8;
        }
        for (; e + 2 <= e1; e += 2) {
            int4 p = csr4[e >> 1];
            int col = g ? p.z : p.x;
            float nrm = __int_as_float(g ? p.w : p.y);
            uint32 u = zq[col * QU + li];
            a0 += nrm * bf16lo(u);
            a1 += nrm * bf16hi(u);
        }
        if (e < e1 && g == 0) {
            int2 p = csr_pack[e];
            float nrm = __int_as_float(p.y);
            uint32 u = zq[p.x * QU + li];
            a0 += nrm * bf16lo(u);
            a1 += nrm * bf16hi(u);
        }
    }
    float o0 = __shfl(a0, li + 24);
    float o1 = __shfl(a1, li + 24);
    if (lane < 24) {
        a0 += o0;
        a1 += o1;
        int idx = (q * N_NODES + node) * QU + li;
        uint32 pu = zprev[idx];
        float v0 = alpha * a0 - beta * bf16lo(pu);
        float v1 = alpha * a1 - beta * bf16hi(pu);
        znext[idx] = pack_bf16(v0, v1);
        zs[wv][2 * li]     = v0;
        zs[wv][2 * li + 1] = v1;
    }
    __syncthreads();
    float* op = out + (size_t)node * BG + q * 128;
#pragma unroll
    for (int r = 0; r < 2; r++) {
        int j = lane + 64 * r;
        int bl = j >> 5, f = j & 31;
        const float* zb = &zs[wv][bl * HLEN];
        float s = 0.f;
#pragma unroll
        for (int h = 0; h < HLEN; h++) s += zb[h] * wk[h * G1 + f];
        op[j] += s;
    }
}

__global__ __launch_bounds__(256) void fc1_kernel(const float* __restrict__ out,
                                                  const float* __restrict__ conv_b,
                                                  const float* __restrict__ fc_w,
                                                  float* __restrict__ partials) {
    int t = threadIdx.x;
    int b = t >> 3;
    int sq = t & 7;
    int f0 = sq * 4;
    float4 cb4 = *(const float4*)(conv_b + f0);

    int n0 = blockIdx.x * 32;
    int n1 = n0 + 32;
    if (n1 > N_NODES) n1 = N_NODES;

    float acc[NCLS];
#pragma unroll
    for (int c = 0; c < NCLS; c++) acc[c] = 0.f;

    for (int n = n0; n < n1; n++) {
        float4 o = *(const float4*)(out + (size_t)n * BG + b * G1 + f0);
        o.x += cb4.x; o.y += cb4.y; o.z += cb4.z; o.w += cb4.w;
        o.x = o.x > 0.f ? o.x : 0.f;
        o.y = o.y > 0.f ? o.y : 0.f;
        o.z = o.z > 0.f ? o.z : 0.f;
        o.w = o.w > 0.f ? o.w : 0.f;
        const float* wp = fc_w + (size_t)n * G1 + f0;
#pragma unroll
        for (int c = 0; c < NCLS; c++) {
            float4 w = *(const float4*)(wp + (size_t)c * (N_NODES * G1));
            acc[c] += o.x * w.x + o.y * w.y + o.z * w.z + o.w * w.w;
        }
    }
#pragma unroll
    for (int c = 0; c < NCLS; c++) {
        float v = acc[c];
        v += __shfl_xor(v, 1);
        v += __shfl_xor(v, 2);
        v += __shfl_xor(v, 4);
        if (sq == 0) partials[(size_t)blockIdx.x * (BATCH * NCLS) + b * NCLS + c] = v;
    }
}

// ---------------- FC final + log_softmax (runtime block count) ----------------
__global__ __launch_bounds__(320) void fc2_kernel(const float* __restrict__ partials,
                                                  const float* __restrict__ fc_b,
                                                  float* __restrict__ outp, int nblocks) {
    __shared__ float lg[BATCH][NCLS];
    int t = threadIdx.x;
    int b = t / NCLS, c = t % NCLS;
    float a0 = 0.f, a1 = 0.f, a2 = 0.f, a3 = 0.f;
    int i = 0;
    for (; i + 4 <= nblocks; i += 4) {
        a0 += partials[(size_t)(i + 0) * (BATCH * NCLS) + t];
        a1 += partials[(size_t)(i + 1) * (BATCH * NCLS) + t];
        a2 += partials[(size_t)(i + 2) * (BATCH * NCLS) + t];
        a3 += partials[(size_t)(i + 3) * (BATCH * NCLS) + t];
    }
    for (; i < nblocks; i++) a0 += partials[(size_t)i * (BATCH * NCLS) + t];
    lg[b][c] = a0 + a1 + a2 + a3 + fc_b[c];
    __syncthreads();
    if (t < BATCH) {
        float v[NCLS];
        float m = -1e30f;
#pragma unroll
        for (int cc = 0; cc < NCLS; cc++) { v[cc] = lg[t][cc]; m = fmaxf(m, v[cc]); }
        float s = 0.f;
#pragma unroll
        for (int cc = 0; cc < NCLS; cc++) s += expf(v[cc] - m);
        float ls = logf(s);
#pragma unroll
        for (int cc = 0; cc < NCLS; cc++) outp[t * NCLS + cc] = v[cc] - m - ls;
    }
}

extern "C" void kernel_launch(void* const* d_in, const int* in_sizes, int n_in,
                              void* d_out, int out_size, void* d_ws, size_t ws_size,
                              hipStream_t stream) {
    const float* x      = (const float*)d_in[0];
    const int*   ei     = (const int*)d_in[1];
    const float* conv_w = (const float*)d_in[2];
    const float* conv_b = (const float*)d_in[3];
    const float* fc_w   = (const float*)d_in[4];
    const float* fc_b   = (const float*)d_in[5];
    float* outp = (float*)d_out;

    const int* row = ei;
    const int* col = ei + N_EDGES;

    const size_t SLAB_U = (size_t)N_NODES * RU;

    char* ws = (char*)d_ws;
    size_t off = 0;
    auto alloc = [&](size_t bytes) -> void* {
        void* p = ws + off;
        off = (off + bytes + 255) & ~(size_t)255;
        return p;
    };
    // common small buffers (~3 MB)
    int*    cnt      = (int*)alloc(sizeof(int) * N_NODES);
    float*  dinv     = (float*)alloc(sizeof(float) * N_NODES);
    int*    rowstart = (int*)alloc(sizeof(int) * (N_NODES + 1));
    int*    cursor   = (int*)alloc(sizeof(int) * N_NODES);
    int2*   csr_pack = (int2*)alloc(sizeof(int2) * N_EDGES);
    uint32* w_pk     = (uint32*)alloc(sizeof(uint32) * WPK_N);
    float*  partials = (float*)alloc(sizeof(float) * FC1_BLOCKS * BATCH * NCLS);
    // red (10x320) aliases cnt (40KB): cnt's last read precedes red1's write.
    float*  red      = (float*)cnt;

    const size_t T_ALL_BYTES = sizeof(uint32) * SLAB_U * KORD;  // 192 MB
    bool big = (ws_size > off && (ws_size - off) >= T_ALL_BYTES + 65536);

    hipMemsetAsync(cnt, 0, sizeof(int) * N_NODES, stream);
    hipMemsetAsync(cursor, 0, sizeof(int) * N_NODES, stream);

    deg_kernel<<<(N_EDGES + 255) / 256, 256, 0, stream>>>(row, cnt);
    dinv_kernel<<<(N_NODES + 255) / 256, 256, 0, stream>>>(cnt, dinv);
    scan_kernel<<<1, 1024, 0, stream>>>(cnt, rowstart);
    scatter_kernel<<<(N_EDGES + 255) / 256, 256, 0, stream>>>(row, col, dinv, rowstart,
                                                              cursor, csr_pack);

    if (big) {
        uint32* T_all = (uint32*)alloc(T_ALL_BYTES);
        wpack_kernel<<<(WPK_N + 255) / 256, 256, 0, stream>>>(conv_w, w_pk);
        fft_full_kernel<<<(N_NODES * BATCH + 255) / 256, 256, 0, stream>>>(x, T_all);
        spmm_full_kernel<<<N_NODES / 4, 256, 0, stream>>>(T_all, T_all, T_all + SLAB_U,
                                                          rowstart, csr_pack, 1.0f, 0.0f);
        for (int k = 2; k < KORD; k++) {
            spmm_full_kernel<<<N_NODES / 4, 256, 0, stream>>>(
                T_all + SLAB_U * (size_t)(k - 1), T_all + SLAB_U * (size_t)(k - 2),
                T_all + SLAB_U * (size_t)k, rowstart, csr_pack, 2.0f, 1.0f);
        }
        einfc_mfma_kernel<<<EIN_BLOCKS, 256, 0, stream>>>(T_all, w_pk, conv_b, fc_w,
                                                          partials);
        red1_kernel<<<RED1_BLOCKS, 320, 0, stream>>>(partials, red);
        fc2_kernel<<<1, 320, 0, stream>>>(red, fc_b, outp, RED1_BLOCKS);
    } else {
        // fallback: R8 structure (~58 MB, proven)
        float*  outacc = (float*)alloc(sizeof(float) * (size_t)N_NODES * BG);
        uint32* slabA  = (uint32*)alloc(sizeof(uint32) * SLAB_U);
        uint32* slabB  = (uint32*)alloc(sizeof(uint32) * SLAB_U);
        const int GRID = (N_NODES / 4) * NQ;

        fft_slice_kernel<<<(N_NODES * BATCH + 255) / 256, 256, 0, stream>>>(
            x, (ushort16*)slabA);
        k0_split_kernel<<<GRID, 256, 0, stream>>>(slabA, outacc, conv_w);
        spmm_fused_kernel<<<GRID, 256, 0, stream>>>(slabA, slabA, slabB, outacc,
                                                    rowstart, csr_pack, conv_w + 1 * BH,
                                                    1.0f, 0.0f);
        uint32* zprev = slabA;
        uint32* zcur  = slabB;
        for (int k = 2; k < KORD; k++) {
            spmm_fused_kernel<<<GRID, 256, 0, stream>>>(zcur, zprev, zprev, outacc,
                                                        rowstart, csr_pack,
                                                        conv_w + (size_t)k * BH,
                                                        2.0f, 1.0f);
            uint32* tmp = zprev; zprev = zcur; zcur = tmp;
        }
        fc1_kernel<<<FC1_BLOCKS, 256, 0, stream>>>(outacc, conv_b, fc_w, partials);
        fc2_kernel<<<1, 320, 0, stream>>>(partials, fc_b, outp, FC1_BLOCKS);
    }
}

// Round 16
// 543.862 us; speedup vs baseline: 1.0700x; 1.0700x over previous
//
#include <hip/hip_runtime.h>
#include <math.h>

#define N_NODES 10000
#define N_EDGES 160000
#define BATCH 32
#define HLEN 12
#define KORD 25
#define G1 32
#define NCLS 10
#define BH 384   /* BATCH*HLEN */
#define BG 1024  /* BATCH*G1  */
#define NQ 8     /* fallback path: BH split into 8 slices of 48 */
#define QW 48
#define QU 24
#define RU 192   /* big path: uints per full bf16 row (384 values) */
#define FC1_BLOCKS 313
#define EIN_BLOCKS 2500
#define RED1_BLOCKS 10
#define WPK_N (KORD * 192)  /* w_pk uints: [KORD][3][2][32] */

typedef unsigned int uint32;
typedef unsigned short ushort16;
typedef __attribute__((ext_vector_type(8))) short short8v;
typedef __attribute__((ext_vector_type(4))) float f32x4;
typedef __attribute__((ext_vector_type(2))) unsigned int uint2v;

struct U3 { uint32 x, y, z; };  // 12B, 4-aligned -> global_load_dwordx3

__device__ __forceinline__ float bf16lo(uint32 u) { return __uint_as_float(u << 16); }
__device__ __forceinline__ float bf16hi(uint32 u) { return __uint_as_float(u & 0xffff0000u); }
__device__ __forceinline__ uint32 pack_bf16(float a, float b) {
    uint32 ua = __float_as_uint(a), ub = __float_as_uint(b);
    ua = (ua + 0x7fffu + ((ua >> 16) & 1u)) >> 16;
    ub = (ub + 0x7fffu + ((ub >> 16) & 1u)) & 0xffff0000u;
    return ua | ub;
}
__device__ __forceinline__ ushort16 f2bf(float a) {
    uint32 ua = __float_as_uint(a);
    return (ushort16)((ua + 0x7fffu + ((ua >> 16) & 1u)) >> 16);
}

// ---------------- CSR build ----------------
__global__ void deg_kernel(const int* __restrict__ row, int* __restrict__ cnt) {
    int e = blockIdx.x * 256 + threadIdx.x;
    if (e < N_EDGES) atomicAdd(&cnt[row[e]], 1);
}

__global__ void dinv_kernel(const int* __restrict__ cnt, float* __restrict__ dinv) {
    int n = blockIdx.x * 256 + threadIdx.x;
    if (n < N_NODES) {
        int d = cnt[n];
        dinv[n] = (d > 0) ? 1.0f / sqrtf((float)d) : 0.0f;
    }
}

__global__ __launch_bounds__(1024) void scan_kernel(const int* __restrict__ cnt,
                                                    int* __restrict__ rowstart) {
    __shared__ int sums[1024];
    int t = threadIdx.x;
    const int per = 10;
    int base = t * per;
    int s = 0;
    for (int i = 0; i < per; i++) { int idx = base + i; if (idx < N_NODES) s += cnt[idx]; }
    sums[t] = s;
    __syncthreads();
    for (int off = 1; off < 1024; off <<= 1) {
        int v = 0;
        if (t >= off) v = sums[t - off];
        __syncthreads();
        sums[t] += v;
        __syncthreads();
    }
    int run = sums[t] - s;
    for (int i = 0; i < per; i++) {
        int idx = base + i;
        if (idx < N_NODES) { rowstart[idx] = run; run += cnt[idx]; }
    }
    if (t == 1023) rowstart[N_NODES] = run;
}

__global__ void scatter_kernel(const int* __restrict__ row, const int* __restrict__ col,
                               const float* __restrict__ dinv,
                               const int* __restrict__ rowstart, int* __restrict__ cursor,
                               int2* __restrict__ csr_pack) {
    int e = blockIdx.x * 256 + threadIdx.x;
    if (e < N_EDGES) {
        int r = row[e], c = col[e];
        int p = rowstart[r] + atomicAdd(&cursor[r], 1);
        float nrm = -dinv[r] * dinv[c];
        csr_pack[p] = make_int2(c, __float_as_int(nrm));
    }
}

// ---------------- bf16 weight pre-pack: w_pk[k][g][j2][f] ----------------
__global__ void wpack_kernel(const float* __restrict__ conv_w, uint32* __restrict__ w_pk) {
    int idx = blockIdx.x * 256 + threadIdx.x;
    if (idx >= WPK_N) return;
    int k = idx / 192;
    int r = idx % 192;
    int g = r >> 6;
    int j2 = (r >> 5) & 1;
    int f = r & 31;
    int h0 = 4 * g + 2 * j2;
    float a = conv_w[(size_t)k * BH + h0 * G1 + f];
    float b = conv_w[(size_t)k * BH + (h0 + 1) * G1 + f];
    w_pk[idx] = pack_bf16(a, b);
}

// ================= BIG PATH (full-row layout [k][node][192 uints]) =================
__global__ __launch_bounds__(256) void fft_full_kernel(const float* __restrict__ x,
                                                       uint32* __restrict__ T0) {
    __shared__ float C[HLEN][HLEN];
    int t = threadIdx.x;
    if (t < HLEN * HLEN) {
        int k = t / HLEN, tt = t % HLEN;
        C[k][tt] = cosf(0.52359877559829887308f * (float)(k * tt)); // pi/6 * k*t
    }
    __syncthreads();
    int tid = blockIdx.x * 256 + t; // tid = n*32 + b
    if (tid >= N_NODES * BATCH) return;
    int n = tid >> 5, b = tid & 31;
    const float* xp = x + (size_t)b * (N_NODES * HLEN) + (size_t)n * HLEN;
    float xr[HLEN];
#pragma unroll
    for (int i = 0; i < HLEN; i++) xr[i] = xp[i];
    float s[HLEN];
#pragma unroll
    for (int k = 0; k < HLEN; k++) {
        float acc = 0.f;
#pragma unroll
        for (int i = 0; i < HLEN; i++) acc += xr[i] * C[k][i];
        s[k] = acc;
    }
    uint32* o = T0 + (size_t)n * RU + b * 6;
#pragma unroll
    for (int j = 0; j < 6; j++) o[j] = pack_bf16(s[2 * j], s[2 * j + 1]);
}

// ---------------- full-row SpMM (dwordx3 lanes; 4-edge chunks, R14-proven) ----------------
__global__ __launch_bounds__(256) void spmm_full_kernel(
    const uint32* __restrict__ zcur, const uint32* __restrict__ zprev,
    uint32* __restrict__ znext,
    const int* __restrict__ rowstart, const int2* __restrict__ csr_pack,
    float alpha, float beta) {
    int t = threadIdx.x;
    int wv = t >> 6, l = t & 63;
    int node = blockIdx.x * 4 + wv;
    int lo3 = 3 * l;

    float a0 = 0.f, a1 = 0.f, a2 = 0.f, a3 = 0.f, a4 = 0.f, a5 = 0.f;
    int e0 = rowstart[node], e1 = rowstart[node + 1];
    int e = e0;
    if ((e & 1) && e < e1) { // odd head
        int2 p = csr_pack[e];
        float nrm = __int_as_float(p.y);
        U3 u = *(const U3*)(zcur + p.x * RU + lo3);
        a0 += nrm * bf16lo(u.x); a1 += nrm * bf16hi(u.x);
        a2 += nrm * bf16lo(u.y); a3 += nrm * bf16hi(u.y);
        a4 += nrm * bf16lo(u.z); a5 += nrm * bf16hi(u.z);
        e++;
    }
    const int4* csr4 = (const int4*)csr_pack;
    int npair = (e1 - e) >> 1;
    int base = e >> 1;
    int nch = npair >> 1; // chunks of 4 edges
    if (nch > 0) {
        int4 c0 = csr4[base], c1 = csr4[base + 1];
        for (int ch = 0; ch < nch; ch++) {
            int4 p0 = c0, p1 = c1;
            if (ch + 1 < nch) {
                c0 = csr4[base + 2 * ch + 2];
                c1 = csr4[base + 2 * ch + 3];
            }
            U3 uA = *(const U3*)(zcur + p0.x * RU + lo3);
            U3 uB = *(const U3*)(zcur + p0.z * RU + lo3);
            U3 uC = *(const U3*)(zcur + p1.x * RU + lo3);
            U3 uD = *(const U3*)(zcur + p1.z * RU + lo3);
            float nA = __int_as_float(p0.y), nB = __int_as_float(p0.w);
            float nC = __int_as_float(p1.y), nD = __int_as_float(p1.w);
            a0 += nA * bf16lo(uA.x) + nB * bf16lo(uB.x) + nC * bf16lo(uC.x) + nD * bf16lo(uD.x);
            a1 += nA * bf16hi(uA.x) + nB * bf16hi(uB.x) + nC * bf16hi(uC.x) + nD * bf16hi(uD.x);
            a2 += nA * bf16lo(uA.y) + nB * bf16lo(uB.y) + nC * bf16lo(uC.y) + nD * bf16lo(uD.y);
            a3 += nA * bf16hi(uA.y) + nB * bf16hi(uB.y) + nC * bf16hi(uC.y) + nD * bf16hi(uD.y);
            a4 += nA * bf16lo(uA.z) + nB * bf16lo(uB.z) + nC * bf16lo(uC.z) + nD * bf16lo(uD.z);
            a5 += nA * bf16hi(uA.z) + nB * bf16hi(uB.z) + nC * bf16hi(uC.z) + nD * bf16hi(uD.z);
        }
        e += nch * 4;
    }
    for (; e + 2 <= e1; e += 2) { // tail pair
        int4 p = csr4[e >> 1];
        U3 uA = *(const U3*)(zcur + p.x * RU + lo3);
        U3 uB = *(const U3*)(zcur + p.z * RU + lo3);
        float nA = __int_as_float(p.y), nB = __int_as_float(p.w);
        a0 += nA * bf16lo(uA.x) + nB * bf16lo(uB.x);
        a1 += nA * bf16hi(uA.x) + nB * bf16hi(uB.x);
        a2 += nA * bf16lo(uA.y) + nB * bf16lo(uB.y);
        a3 += nA * bf16hi(uA.y) + nB * bf16hi(uB.y);
        a4 += nA * bf16lo(uA.z) + nB * bf16lo(uB.z);
        a5 += nA * bf16hi(uA.z) + nB * bf16hi(uB.z);
    }
    if (e < e1) { // single tail
        int2 p = csr_pack[e];
        float nrm = __int_as_float(p.y);
        U3 u = *(const U3*)(zcur + p.x * RU + lo3);
        a0 += nrm * bf16lo(u.x); a1 += nrm * bf16hi(u.x);
        a2 += nrm * bf16lo(u.y); a3 += nrm * bf16hi(u.y);
        a4 += nrm * bf16lo(u.z); a5 += nrm * bf16hi(u.z);
    }
    int idx = node * RU + lo3;
    U3 pu = *(const U3*)(zprev + idx);
    U3 ov;
    ov.x = pack_bf16(alpha * a0 - beta * bf16lo(pu.x), alpha * a1 - beta * bf16hi(pu.x));
    ov.y = pack_bf16(alpha * a2 - beta * bf16lo(pu.y), alpha * a3 - beta * bf16hi(pu.y));
    ov.z = pack_bf16(alpha * a4 - beta * bf16lo(pu.z), alpha * a5 - beta * bf16hi(pu.z));
    *(U3*)(znext + idx) = ov;
}

// ---------------- MFMA einsum + relu + FC partial (1 node/wave; w_pk in LDS) ----------------
__global__ __launch_bounds__(256) void einfc_mfma_kernel(
    const uint32* __restrict__ T_all,   // [KORD][N][RU]
    const uint32* __restrict__ w_pk,    // [KORD][3][2][32]
    const float* __restrict__ conv_b,
    const float* __restrict__ fc_w,     // [NCLS][N*G1]
    float* __restrict__ partials) {
    __shared__ float lgacc[BATCH * NCLS];
    __shared__ uint32 wlds[WPK_N];      // 19.2 KB: weights staged once per block
    int t = threadIdx.x;
    for (int i = t; i < BATCH * NCLS; i += 256) lgacc[i] = 0.f;
    for (int i = t; i < WPK_N; i += 256) wlds[i] = w_pk[i];
    __syncthreads();
    int wv = t >> 6, l = t & 63;
    int node = blockIdx.x * 4 + wv;
    int g = l >> 4;     // k-group
    int m = l & 15;     // row/col within 16-tile
    bool gz = (g == 3); // pad group (h 12..15)

    f32x4 acc00 = {0.f, 0.f, 0.f, 0.f};
    f32x4 acc01 = {0.f, 0.f, 0.f, 0.f};
    f32x4 acc10 = {0.f, 0.f, 0.f, 0.f};
    f32x4 acc11 = {0.f, 0.f, 0.f, 0.f};

    size_t aoff0 = (size_t)m * 6 + 2 * g;
    size_t aoff1 = (size_t)(m + 16) * 6 + 2 * g;

#pragma unroll
    for (int k = 0; k < KORD; k++) {
        const uint32* row = T_all + ((size_t)k * N_NODES + node) * RU;
        uint2v a0 = {0, 0}, a1 = {0, 0};
        uint32 b0u0 = 0, b0u1 = 0, b1u0 = 0, b1u1 = 0;
        if (!gz) {
            a0 = __builtin_nontemporal_load((const uint2v*)(row + aoff0));
            a1 = __builtin_nontemporal_load((const uint2v*)(row + aoff1));
            const uint32* wp = wlds + (k * 3 + g) * 64 + m;   // LDS path (lgkm queue)
            b0u0 = wp[0];  b0u1 = wp[32];
            b1u0 = wp[16]; b1u1 = wp[48];
        }
        union { short8v v; uint32 u[4]; } A0, A1, B0, B1;
        A0.u[0] = a0.x; A0.u[1] = a0.y; A0.u[2] = 0; A0.u[3] = 0;
        A1.u[0] = a1.x; A1.u[1] = a1.y; A1.u[2] = 0; A1.u[3] = 0;
        B0.u[0] = b0u0; B0.u[1] = b0u1; B0.u[2] = 0; B0.u[3] = 0;
        B1.u[0] = b1u0; B1.u[1] = b1u1; B1.u[2] = 0; B1.u[3] = 0;
        acc00 = __builtin_amdgcn_mfma_f32_16x16x32_bf16(A0.v, B0.v, acc00, 0, 0, 0);
        acc01 = __builtin_amdgcn_mfma_f32_16x16x32_bf16(A0.v, B1.v, acc01, 0, 0, 0);
        acc10 = __builtin_amdgcn_mfma_f32_16x16x32_bf16(A1.v, B0.v, acc10, 0, 0, 0);
        acc11 = __builtin_amdgcn_mfma_f32_16x16x32_bf16(A1.v, B1.v, acc11, 0, 0, 0);
    }

    // epilogue: relu + FC partial from C layout (col=lane&15, row=4*(lane>>4)+reg)
    float cb0 = conv_b[m];
    float cb1 = conv_b[m + 16];
    float fw0[NCLS], fw1[NCLS];
#pragma unroll
    for (int c = 0; c < NCLS; c++) {
        const float* fp = fc_w + (size_t)c * (N_NODES * G1) + (size_t)node * G1;
        fw0[c] = fp[m];
        fw1[c] = fp[m + 16];
    }
#pragma unroll
    for (int bi = 0; bi < 2; bi++) {
        f32x4 aF = bi ? acc10 : acc00;
        f32x4 aS = bi ? acc11 : acc01;
#pragma unroll
        for (int reg = 0; reg < 4; reg++) {
            float h0 = fmaxf(aF[reg] + cb0, 0.f);
            float h1 = fmaxf(aS[reg] + cb1, 0.f);
            int b = bi * 16 + 4 * g + reg;
#pragma unroll
            for (int c = 0; c < NCLS; c++) {
                float sc = h0 * fw0[c] + h1 * fw1[c];
                sc += __shfl_xor(sc, 1);
                sc += __shfl_xor(sc, 2);
                sc += __shfl_xor(sc, 4);
                sc += __shfl_xor(sc, 8);
                if (m == 0) atomicAdd(&lgacc[b * NCLS + c], sc);
            }
        }
    }
    __syncthreads();
    for (int i = t; i < BATCH * NCLS; i += 256)
        partials[(size_t)blockIdx.x * (BATCH * NCLS) + i] = lgacc[i];
}

// ---------------- partial-reduce stage: EIN_BLOCKS rows -> 10 rows ----------------
__global__ __launch_bounds__(320) void red1_kernel(const float* __restrict__ partials,
                                                   float* __restrict__ red) {
    int t = threadIdx.x;
    int j = blockIdx.x;
    int i0 = j * (EIN_BLOCKS / RED1_BLOCKS);
    int i1 = i0 + (EIN_BLOCKS / RED1_BLOCKS);
    float s0 = 0.f, s1 = 0.f, s2 = 0.f, s3 = 0.f;
    int i = i0;
    for (; i + 4 <= i1; i += 4) {
        s0 += partials[(size_t)(i + 0) * (BATCH * NCLS) + t];
        s1 += partials[(size_t)(i + 1) * (BATCH * NCLS) + t];
        s2 += partials[(size_t)(i + 2) * (BATCH * NCLS) + t];
        s3 += partials[(size_t)(i + 3) * (BATCH * NCLS) + t];
    }
    for (; i < i1; i++) s0 += partials[(size_t)i * (BATCH * NCLS) + t];
    red[(size_t)j * (BATCH * NCLS) + t] = s0 + s1 + s2 + s3;
}

// ================= FALLBACK PATH (R8, proven; slice layout) =================
__global__ __launch_bounds__(256) void fft_slice_kernel(const float* __restrict__ x,
                                                        ushort16* __restrict__ xf) {
    __shared__ float C[HLEN][HLEN];
    int t = threadIdx.x;
    if (t < HLEN * HLEN) {
        int k = t / HLEN, tt = t % HLEN;
        C[k][tt] = cosf(0.52359877559829887308f * (float)(k * tt));
    }
    __syncthreads();
    int tid = blockIdx.x * 256 + t;
    if (tid >= N_NODES * BATCH) return;
    int n = tid >> 5, b = tid & 31;
    const float* xp = x + (size_t)b * (N_NODES * HLEN) + (size_t)n * HLEN;
    float xr[HLEN];
#pragma unroll
    for (int i = 0; i < HLEN; i++) xr[i] = xp[i];
    int q = b >> 2, bl = b & 3;
    ushort16* o = xf + ((size_t)q * N_NODES + n) * QW + bl * HLEN;
#pragma unroll
    for (int k = 0; k < HLEN; k++) {
        float s = 0.f;
#pragma unroll
        for (int i = 0; i < HLEN; i++) s += xr[i] * C[k][i];
        o[k] = f2bf(s);
    }
}

__global__ __launch_bounds__(256) void k0_split_kernel(const uint32* __restrict__ z,
                                                       float* __restrict__ out,
                                                       const float* __restrict__ w0) {
    __shared__ float zs[4][QW];
    __shared__ float wk[HLEN * G1];
    int t = threadIdx.x;
    int wv = t >> 6, lane = t & 63;
    int bid = blockIdx.x;
    int q = bid & 7;
    int node = (bid >> 3) * 4 + wv;
    for (int i = t; i < HLEN * G1; i += 256) wk[i] = w0[i];
    if (lane < QU) {
        uint32 u = z[((size_t)q * N_NODES + node) * QU + lane];
        zs[wv][2 * lane]     = bf16lo(u);
        zs[wv][2 * lane + 1] = bf16hi(u);
    }
    __syncthreads();
    float* op = out + (size_t)node * BG + q * 128;
#pragma unroll
    for (int r = 0; r < 2; r++) {
        int j = lane + 64 * r;
        int bl = j >> 5, f = j & 31;
        const float* zb = &zs[wv][bl * HLEN];
        float s = 0.f;
#pragma unroll
        for (int h = 0; h < HLEN; h++) s += zb[h] * wk[h * G1 + f];
        op[j] = s;
    }
}

__global__ __launch_bounds__(256) void spmm_fused_kernel(
    const uint32* __restrict__ zcur, const uint32* __restrict__ zprev,
    uint32* __restrict__ znext, float* __restrict__ out,
    const int* __restrict__ rowstart, const int2* __restrict__ csr_pack,
    const float* __restrict__ wkg, float alpha, float beta) {
    __shared__ float zs[4][QW];
    __shared__ float wk[HLEN * G1];
    int t = threadIdx.x;
    int wv = t >> 6, lane = t & 63;
    int bid = blockIdx.x;
    int q = bid & 7;
    int node = (bid >> 3) * 4 + wv;
    for (int i = t; i < HLEN * G1; i += 256) wk[i] = wkg[i];

    const uint32* zq = zcur + (size_t)q * ((size_t)N_NODES * QU);
    int g  = (lane >= 24) ? 1 : 0;
    int li = lane - g * 24;
    float a0 = 0.f, a1 = 0.f;
    int e0 = rowstart[node], e1 = rowstart[node + 1];
    if (lane < 48) {
        int e = e0;
        if ((e & 1) && e < e1) {
            if (g == 0) {
                int2 p = csr_pack[e];
                float nrm = __int_as_float(p.y);
                uint32 u = zq[p.x * QU + li];
                a0 += nrm * bf16lo(u);
                a1 += nrm * bf16hi(u);
            }
            e++;
        }
        const int4* csr4 = (const int4*)csr_pack;
        int npair = (e1 - e) >> 1;
        int base = e >> 1;
        int nchunk = npair >> 2;
        if (nchunk > 0) {
            int4 c0 = csr4[base];
            int4 c1 = csr4[base + 1];
            int4 c2 = csr4[base + 2];
            int4 c3 = csr4[base + 3];
            for (int ch = 0; ch < nchunk; ch++) {
                int4 p0 = c0, p1 = c1, p2 = c2, p3 = c3;
                if (ch + 1 < nchunk) {
                    int b2 = base + (ch + 1) * 4;
                    c0 = csr4[b2];
                    c1 = csr4[b2 + 1];
                    c2 = csr4[b2 + 2];
                    c3 = csr4[b2 + 3];
                }
                int col0 = g ? p0.z : p0.x;  float n0 = __int_as_float(g ? p0.w : p0.y);
                int col1 = g ? p1.z : p1.x;  float n1 = __int_as_float(g ? p1.w : p1.y);
                int col2 = g ? p2.z : p2.x;  float n2 = __int_as_float(g ? p2.w : p2.y);
                int col3 = g ? p3.z : p3.x;  float n3 = __int_as_float(g ? p3.w : p3.y);
                uint32 u0 = zq[col0 * QU + li];
                uint32 u1 = zq[col1 * QU + li];
                uint32 u2 = zq[col2 * QU + li];
                uint32 u3 = zq[col3 * QU + li];
                a0 += n0 * bf16lo(u0) + n1 * bf16lo(u1);
                a1 += n0 * bf16hi(u0) + n1 * bf16hi(u1);
                a0 += n2 * bf16lo(u2) + n3 * bf16lo(u3);
                a1 += n2 * bf16hi(u2) + n3 * bf16hi(u3);
            }
            e += nchunk * 8;
        }
        for (; e + 2 <= e1; e += 2) {
            int4 p = csr4[e >> 1];
            int col = g ? p.z : p.x;
            float nrm = __int_as_float(g ? p.w : p.y);
            uint32 u = zq[col * QU + li];
            a0 += nrm * bf16lo(u);
            a1 += nrm * bf16hi(u);
        }
        if (e < e1 && g == 0) {
            int2 p = csr_pack[e];
            float nrm = __int_as_float(p.y);
            uint32 u = zq[p.x * QU + li];
            a0 += nrm * bf16lo(u);
            a1 += nrm * bf16hi(u);
        }
    }
    float o0 = __shfl(a0, li + 24);
    float o1 = __shfl(a1, li + 24);
    if (lane < 24) {
        a0 += o0;
        a1 += o1;
        int idx = (q * N_NODES + node) * QU + li;
        uint32 pu = zprev[idx];
        float v0 = alpha * a0 - beta * bf16lo(pu);
        float v1 = alpha * a1 - beta * bf16hi(pu);
        znext[idx] = pack_bf16(v0, v1);
        zs[wv][2 * li]     = v0;
        zs[wv][2 * li + 1] = v1;
    }
    __syncthreads();
    float* op = out + (size_t)node * BG + q * 128;
#pragma unroll
    for (int r = 0; r < 2; r++) {
        int j = lane + 64 * r;
        int bl = j >> 5, f = j & 31;
        const float* zb = &zs[wv][bl * HLEN];
        float s = 0.f;
#pragma unroll
        for (int h = 0; h < HLEN; h++) s += zb[h] * wk[h * G1 + f];
        op[j] += s;
    }
}

__global__ __launch_bounds__(256) void fc1_kernel(const float* __restrict__ out,
                                                  const float* __restrict__ conv_b,
                                                  const float* __restrict__ fc_w,
                                                  float* __restrict__ partials) {
    int t = threadIdx.x;
    int b = t >> 3;
    int sq = t & 7;
    int f0 = sq * 4;
    float4 cb4 = *(const float4*)(conv_b + f0);

    int n0 = blockIdx.x * 32;
    int n1 = n0 + 32;
    if (n1 > N_NODES) n1 = N_NODES;

    float acc[NCLS];
#pragma unroll
    for (int c = 0; c < NCLS; c++) acc[c] = 0.f;

    for (int n = n0; n < n1; n++) {
        float4 o = *(const float4*)(out + (size_t)n * BG + b * G1 + f0);
        o.x += cb4.x; o.y += cb4.y; o.z += cb4.z; o.w += cb4.w;
        o.x = o.x > 0.f ? o.x : 0.f;
        o.y = o.y > 0.f ? o.y : 0.f;
        o.z = o.z > 0.f ? o.z : 0.f;
        o.w = o.w > 0.f ? o.w : 0.f;
        const float* wp = fc_w + (size_t)n * G1 + f0;
#pragma unroll
        for (int c = 0; c < NCLS; c++) {
            float4 w = *(const float4*)(wp + (size_t)c * (N_NODES * G1));
            acc[c] += o.x * w.x + o.y * w.y + o.z * w.z + o.w * w.w;
        }
    }
#pragma unroll
    for (int c = 0; c < NCLS; c++) {
        float v = acc[c];
        v += __shfl_xor(v, 1);
        v += __shfl_xor(v, 2);
        v += __shfl_xor(v, 4);
        if (sq == 0) partials[(size_t)blockIdx.x * (BATCH * NCLS) + b * NCLS + c] = v;
    }
}

// ---------------- FC final + log_softmax (runtime block count) ----------------
__global__ __launch_bounds__(320) void fc2_kernel(const float* __restrict__ partials,
                                                  const float* __restrict__ fc_b,
                                                  float* __restrict__ outp, int nblocks) {
    __shared__ float lg[BATCH][NCLS];
    int t = threadIdx.x;
    int b = t / NCLS, c = t % NCLS;
    float a0 = 0.f, a1 = 0.f, a2 = 0.f, a3 = 0.f;
    int i = 0;
    for (; i + 4 <= nblocks; i += 4) {
        a0 += partials[(size_t)(i + 0) * (BATCH * NCLS) + t];
        a1 += partials[(size_t)(i + 1) * (BATCH * NCLS) + t];
        a2 += partials[(size_t)(i + 2) * (BATCH * NCLS) + t];
        a3 += partials[(size_t)(i + 3) * (BATCH * NCLS) + t];
    }
    for (; i < nblocks; i++) a0 += partials[(size_t)i * (BATCH * NCLS) + t];
    lg[b][c] = a0 + a1 + a2 + a3 + fc_b[c];
    __syncthreads();
    if (t < BATCH) {
        float v[NCLS];
        float m = -1e30f;
#pragma unroll
        for (int cc = 0; cc < NCLS; cc++) { v[cc] = lg[t][cc]; m = fmaxf(m, v[cc]); }
        float s = 0.f;
#pragma unroll
        for (int cc = 0; cc < NCLS; cc++) s += expf(v[cc] - m);
        float ls = logf(s);
#pragma unroll
        for (int cc = 0; cc < NCLS; cc++) outp[t * NCLS + cc] = v[cc] - m - ls;
    }
}

extern "C" void kernel_launch(void* const* d_in, const int* in_sizes, int n_in,
                              void* d_out, int out_size, void* d_ws, size_t ws_size,
                              hipStream_t stream) {
    const float* x      = (const float*)d_in[0];
    const int*   ei     = (const int*)d_in[1];
    const float* conv_w = (const float*)d_in[2];
    const float* conv_b = (const float*)d_in[3];
    const float* fc_w   = (const float*)d_in[4];
    const float* fc_b   = (const float*)d_in[5];
    float* outp = (float*)d_out;

    const int* row = ei;
    const int* col = ei + N_EDGES;

    const size_t SLAB_U = (size_t)N_NODES * RU;

    char* ws = (char*)d_ws;
    size_t off = 0;
    auto alloc = [&](size_t bytes) -> void* {
        void* p = ws + off;
        off = (off + bytes + 255) & ~(size_t)255;
        return p;
    };
    // common small buffers (~7.9 MB) -- partials sized for EIN_BLOCKS (bug fix vs R14)
    int*    cnt      = (int*)alloc(sizeof(int) * N_NODES);
    float*  dinv     = (float*)alloc(sizeof(float) * N_NODES);
    int*    rowstart = (int*)alloc(sizeof(int) * (N_NODES + 1));
    int*    cursor   = (int*)alloc(sizeof(int) * N_NODES);
    int2*   csr_pack = (int2*)alloc(sizeof(int2) * N_EDGES);
    uint32* w_pk     = (uint32*)alloc(sizeof(uint32) * WPK_N);
    float*  partials = (float*)alloc(sizeof(float) * EIN_BLOCKS * BATCH * NCLS);
    // red (10x320) aliases cnt (40KB): cnt's last read precedes red1's write.
    float*  red      = (float*)cnt;

    const size_t T_ALL_BYTES = sizeof(uint32) * SLAB_U * KORD;  // 192 MB
    bool big = (ws_size > off && (ws_size - off) >= T_ALL_BYTES + 65536);

    hipMemsetAsync(cnt, 0, sizeof(int) * N_NODES, stream);
    hipMemsetAsync(cursor, 0, sizeof(int) * N_NODES, stream);

    deg_kernel<<<(N_EDGES + 255) / 256, 256, 0, stream>>>(row, cnt);
    dinv_kernel<<<(N_NODES + 255) / 256, 256, 0, stream>>>(cnt, dinv);
    scan_kernel<<<1, 1024, 0, stream>>>(cnt, rowstart);
    scatter_kernel<<<(N_EDGES + 255) / 256, 256, 0, stream>>>(row, col, dinv, rowstart,
                                                              cursor, csr_pack);

    if (big) {
        uint32* T_all = (uint32*)alloc(T_ALL_BYTES);
        wpack_kernel<<<(WPK_N + 255) / 256, 256, 0, stream>>>(conv_w, w_pk);
        fft_full_kernel<<<(N_NODES * BATCH + 255) / 256, 256, 0, stream>>>(x, T_all);
        spmm_full_kernel<<<N_NODES / 4, 256, 0, stream>>>(T_all, T_all, T_all + SLAB_U,
                                                          rowstart, csr_pack, 1.0f, 0.0f);
        for (int k = 2; k < KORD; k++) {
            spmm_full_kernel<<<N_NODES / 4, 256, 0, stream>>>(
                T_all + SLAB_U * (size_t)(k - 1), T_all + SLAB_U * (size_t)(k - 2),
                T_all + SLAB_U * (size_t)k, rowstart, csr_pack, 2.0f, 1.0f);
        }
        einfc_mfma_kernel<<<EIN_BLOCKS, 256, 0, stream>>>(T_all, w_pk, conv_b, fc_w,
                                                          partials);
        red1_kernel<<<RED1_BLOCKS, 320, 0, stream>>>(partials, red);
        fc2_kernel<<<1, 320, 0, stream>>>(red, fc_b, outp, RED1_BLOCKS);
    } else {
        // fallback: R8 structure (~58 MB, proven)
        float*  outacc = (float*)alloc(sizeof(float) * (size_t)N_NODES * BG);
        uint32* slabA  = (uint32*)alloc(sizeof(uint32) * SLAB_U);
        uint32* slabB  = (uint32*)alloc(sizeof(uint32) * SLAB_U);
        const int GRID = (N_NODES / 4) * NQ;

        fft_slice_kernel<<<(N_NODES * BATCH + 255) / 256, 256, 0, stream>>>(
            x, (ushort16*)slabA);
        k0_split_kernel<<<GRID, 256, 0, stream>>>(slabA, outacc, conv_w);
        spmm_fused_kernel<<<GRID, 256, 0, stream>>>(slabA, slabA, slabB, outacc,
                                                    rowstart, csr_pack, conv_w + 1 * BH,
                                                    1.0f, 0.0f);
        uint32* zprev = slabA;
        uint32* zcur  = slabB;
        for (int k = 2; k < KORD; k++) {
            spmm_fused_kernel<<<GRID, 256, 0, stream>>>(zcur, zprev, zprev, outacc,
                                                        rowstart, csr_pack,
                                                        conv_w + (size_t)k * BH,
                                                        2.0f, 1.0f);
            uint32* tmp = zprev; zprev = zcur; zcur = tmp;
        }
        fc1_kernel<<<FC1_BLOCKS, 256, 0, stream>>>(outacc, conv_b, fc_w, partials);
        fc2_kernel<<<1, 320, 0, stream>>>(partials, fc_b, outp, FC1_BLOCKS);
    }
}